// Round 1
// baseline (4492.718 us; speedup 1.0000x reference)
//
#include <hip/hip_runtime.h>
#include <cstdint>

// LSTM fused kernel for MI355X.
// Strategy: 1 block per batch element (64 blocks x 512 threads), full T-loop
// in-kernel. W_hh int8 (per-row scale) RESIDENT IN VGPRS (160 dwords/thread),
// h quantized per-step with dynamic scale, gates via v_dot4_i32_i8.
// x-path uses hi+lo int8 split for both W_ih and x (precision).
// fc (256->32) in fp32 from LDS each step. Prep kernels quantize per launch.

#define B_  64
#define T_  2048
#define I_  32
#define H_  256
#define G4  1024
#define O_  32

#if __has_builtin(__builtin_amdgcn_sdot4)
__device__ __forceinline__ int dot4(int a, int b, int c) {
    return __builtin_amdgcn_sdot4(a, b, c, false);
}
#else
__device__ __forceinline__ int dot4(int a, int b, int c) {
    c += (int)(int8_t)(a)        * (int)(int8_t)(b);
    c += (int)(int8_t)(a >> 8)   * (int)(int8_t)(b >> 8);
    c += (int)(int8_t)(a >> 16)  * (int)(int8_t)(b >> 16);
    c += (int)(int8_t)(a >> 24)  * (int)(int8_t)(b >> 24);
    return c;
}
#endif

// ---------------- ws layout ----------------
// qw   : uint32 [160][512]           (0)        327680 B
// sw1  : float  [1024]               (327680)   4096 B   W_hh row scale (max/127)
// sw2  : float  [1024]               (331776)   4096 B   W_ih row scale
// bias : float  [1024]               (335872)   4096 B   b_ih + b_hh
// xq   : uint32 [B*T][16]            (339968)   8388608 B  (8 dw A, 8 dw B)
// xs   : float  [B*T]                (8728576)  524288 B
#define QW_OFF   0
#define SW1_OFF  327680
#define SW2_OFF  331776
#define BIAS_OFF 335872
#define XQ_OFF   339968
#define XS_OFF   8728576

__device__ __forceinline__ uint32_t pack_q(int q0, int q1, int q2, int q3) {
    return  ((uint32_t)(uint8_t)(int8_t)q0)
          | (((uint32_t)(uint8_t)(int8_t)q1) << 8)
          | (((uint32_t)(uint8_t)(int8_t)q2) << 16)
          | (((uint32_t)(uint8_t)(int8_t)q3) << 24);
}

__device__ __forceinline__ int clamp127(int v) {
    return v < -127 ? -127 : (v > 127 ? 127 : v);
}

// -------- prep: quantize weights (1 block per gate-row, 128 thr) --------
__global__ __launch_bounds__(128) void prep_w(
    const float* __restrict__ Whh, const float* __restrict__ Wih,
    const float* __restrict__ bih, const float* __restrict__ bhh,
    uint32_t* __restrict__ qw, float* __restrict__ sw1,
    float* __restrict__ sw2, float* __restrict__ bias)
{
    const int r = blockIdx.x;
    const int t = threadIdx.x;
    __shared__ float red[128];

    float m = 0.f;
    for (int k = t; k < H_; k += 128) m = fmaxf(m, fabsf(Whh[r * H_ + k]));
    red[t] = m; __syncthreads();
    for (int s = 64; s > 0; s >>= 1) {
        if (t < s) red[t] = fmaxf(red[t], red[t + s]);
        __syncthreads();
    }
    const float m1 = red[0];
    __syncthreads();
    red[t] = (t < I_) ? fabsf(Wih[r * I_ + t]) : 0.f;
    __syncthreads();
    for (int s = 64; s > 0; s >>= 1) {
        if (t < s) red[t] = fmaxf(red[t], red[t + s]);
        __syncthreads();
    }
    const float m2 = red[0];

    const float S1 = fmaxf(m1, 1e-20f) / 127.f;
    const float S2 = fmaxf(m2, 1e-20f) / 127.f;
    const int half = r & 1, rr = r >> 1;

    if (t < 64) {
        int q[4];
        for (int e = 0; e < 4; e++)
            q[e] = clamp127((int)rintf(Whh[r * H_ + t * 4 + e] / S1));
        qw[(half * 80 + t) * 512 + rr] = pack_q(q[0], q[1], q[2], q[3]);
    } else if (t < 72) {
        const int j = t - 64;
        int qa[4], qb[4];
        for (int e = 0; e < 4; e++) {
            float w = Wih[r * I_ + j * 4 + e] / S2;
            int a = clamp127((int)rintf(w));
            int b = clamp127((int)rintf((w - (float)a) * 127.f));
            qa[e] = a; qb[e] = b;
        }
        qw[(half * 80 + 64 + j) * 512 + rr] = pack_q(qa[0], qa[1], qa[2], qa[3]);
        qw[(half * 80 + 72 + j) * 512 + rr] = pack_q(qb[0], qb[1], qb[2], qb[3]);
    }
    if (t == 0) { sw1[r] = S1; sw2[r] = S2; bias[r] = bih[r] + bhh[r]; }
}

// -------- prep: quantize x (64 (b,t) rows per block) --------
__global__ __launch_bounds__(256) void prep_x(
    const float* __restrict__ x, uint32_t* __restrict__ xq, float* __restrict__ xs)
{
    __shared__ float xb[64 * 32];
    const int base = blockIdx.x * 64 * 32;
    for (int i = threadIdx.x; i < 2048; i += 256) xb[i] = x[base + i];
    __syncthreads();
    const int t = threadIdx.x;
    if (t < 64) {
        float m = 0.f;
        for (int k = 0; k < 32; k++) m = fmaxf(m, fabsf(xb[t * 32 + k]));
        const float S = fmaxf(m, 1e-20f) / 127.f;
        const int row = blockIdx.x * 64 + t;
        xs[row] = S;
        for (int j = 0; j < 8; j++) {
            int qa[4], qb[4];
            for (int e = 0; e < 4; e++) {
                float v = xb[t * 32 + j * 4 + e] / S;
                int a = clamp127((int)rintf(v));
                int b = clamp127((int)rintf((v - (float)a) * 127.f));
                qa[e] = a; qb[e] = b;
            }
            xq[row * 16 + j]     = pack_q(qa[0], qa[1], qa[2], qa[3]);
            xq[row * 16 + 8 + j] = pack_q(qb[0], qb[1], qb[2], qb[3]);
        }
    }
}

// -------- main: full LSTM + fc, one block per batch --------
__global__ __launch_bounds__(512, 2) void lstm_main(
    const uint32_t* __restrict__ qw, const float* __restrict__ sw1,
    const float* __restrict__ sw2, const float* __restrict__ bias,
    const uint32_t* __restrict__ xq, const float* __restrict__ xs,
    const float* __restrict__ fcw, const float* __restrict__ fcb,
    float* __restrict__ out)
{
    const int b   = blockIdx.x;
    const int tid = threadIdx.x;

    __shared__ __align__(16) float   fcw_s[O_ * H_];  // 32 KB fp32
    __shared__ __align__(16) uint4   hq4[16];         // 256 int8 h
    __shared__ __align__(16) float   hf[H_];          // fp32 h for fc
    __shared__ __align__(16) float   gates[G4];
    __shared__ float wmax[4];
    __shared__ float shs[1];

    for (int i = tid; i < O_ * H_; i += 512) fcw_s[i] = fcw[i];
    if (tid < 16) hq4[tid] = make_uint4(0u, 0u, 0u, 0u);
    if (tid == 0) shs[0] = 1.f / 127.f;

    // resident int8 weights: w[0..63] row0 Whh, [64..71] row0 Wih-A,
    // [72..79] row0 Wih-B, [80..159] same for row1.
    uint32_t w[160];
    #pragma unroll
    for (int i = 0; i < 160; i++) w[i] = qw[i * 512 + tid];

    const int r0 = 2 * tid, r1 = 2 * tid + 1;
    const float S1a = sw1[r0], S1b = sw1[r1];
    const float S2a = sw2[r0], S2b = sw2[r1];
    const float Ba = bias[r0], Bb = bias[r1];
    const float fcb_v = fcb[tid >> 4];

    float c_state = 0.f;  // valid for tid < 256
    __syncthreads();

    const uint32_t* xqb  = xq + (size_t)(b * T_) * 16;
    const float*    xsb  = xs + (size_t)b * T_;
    float*          outb = out + (size_t)b * T_ * O_;

    for (int t = 0; t < T_; t++) {
        // uniform x loads (scalar path)
        uint32_t xa[8], xbv[8];
        #pragma unroll
        for (int j = 0; j < 8; j++) { xa[j] = xqb[t * 16 + j]; xbv[j] = xqb[t * 16 + 8 + j]; }
        const float Sx = xsb[t];
        const float Sh = shs[0];

        int ah0 = 0, ah1 = 0, ah2 = 0, ah3 = 0;
        #pragma unroll
        for (int d = 0; d < 16; d++) {
            const uint4 hv = hq4[d];   // same-address broadcast, conflict-free
            ah0 = dot4((int)w[d * 4 + 0],      (int)hv.x, ah0);
            ah1 = dot4((int)w[d * 4 + 1],      (int)hv.y, ah1);
            ah0 = dot4((int)w[d * 4 + 2],      (int)hv.z, ah0);
            ah1 = dot4((int)w[d * 4 + 3],      (int)hv.w, ah1);
            ah2 = dot4((int)w[80 + d * 4 + 0], (int)hv.x, ah2);
            ah3 = dot4((int)w[80 + d * 4 + 1], (int)hv.y, ah3);
            ah2 = dot4((int)w[80 + d * 4 + 2], (int)hv.z, ah2);
            ah3 = dot4((int)w[80 + d * 4 + 3], (int)hv.w, ah3);
        }
        int aA0 = 0, aM0 = 0, aA1 = 0, aM1 = 0;
        #pragma unroll
        for (int j = 0; j < 8; j++) {
            aA0 = dot4((int)w[64 + j],  (int)xa[j],  aA0);
            aM0 = dot4((int)w[64 + j],  (int)xbv[j], aM0);
            aM0 = dot4((int)w[72 + j],  (int)xa[j],  aM0);
            aA1 = dot4((int)w[144 + j], (int)xa[j],  aA1);
            aM1 = dot4((int)w[144 + j], (int)xbv[j], aM1);
            aM1 = dot4((int)w[152 + j], (int)xa[j],  aM1);
        }
        const float g0 = (float)(ah0 + ah1) * (S1a * Sh)
                       + ((float)aA0 + (float)aM0 * (1.f / 127.f)) * (S2a * Sx) + Ba;
        const float g1 = (float)(ah2 + ah3) * (S1b * Sh)
                       + ((float)aA1 + (float)aM1 * (1.f / 127.f)) * (S2b * Sx) + Bb;
        gates[r0] = g0;
        gates[r1] = g1;
        __syncthreads();                                   // B1

        float hval = 0.f;
        if (tid < H_) {
            const float gi = gates[tid];
            const float gf = gates[tid + 256];
            const float gg = gates[tid + 512];
            const float go = gates[tid + 768];
            const float i_ = 1.f / (1.f + __expf(-gi));
            const float f_ = 1.f / (1.f + __expf(-gf));
            const float g_ = 2.f / (1.f + __expf(-2.f * gg)) - 1.f;
            const float o_ = 1.f / (1.f + __expf(-go));
            c_state = f_ * c_state + i_ * g_;
            const float tc = 2.f / (1.f + __expf(-2.f * c_state)) - 1.f;
            hval = o_ * tc;
        }
        // block max of |h| (waves 0..3 carry h)
        float m = fabsf(hval);
        #pragma unroll
        for (int s = 1; s < 64; s <<= 1) m = fmaxf(m, __shfl_xor(m, s, 64));
        if (tid < H_ && (tid & 63) == 0) wmax[tid >> 6] = m;
        __syncthreads();                                   // B2

        if (tid < H_) {
            const float mm = fmaxf(fmaxf(wmax[0], wmax[1]), fmaxf(wmax[2], wmax[3]));
            const float Shn = fmaxf(mm, 1e-12f) * (1.f / 127.f);
            int q = clamp127((int)rintf(hval / Shn));
            ((int8_t*)hq4)[tid] = (int8_t)q;
            hf[tid] = hval;
            if (tid == 0) shs[0] = Shn;
        }
        __syncthreads();                                   // B3

        // fc: o = tid>>4 in [0,32), kc = tid&15 covers k in [16kc, 16kc+16)
        {
            const int o = tid >> 4, kc = tid & 15;
            const float4* wr = (const float4*)(fcw_s + o * H_ + kc * 16);
            const float4* hr = (const float4*)(hf + kc * 16);
            float acc = 0.f;
            #pragma unroll
            for (int k = 0; k < 4; k++) {
                const float4 wv = wr[k], hv = hr[k];
                acc += wv.x * hv.x + wv.y * hv.y + wv.z * hv.z + wv.w * hv.w;
            }
            #pragma unroll
            for (int s = 1; s < 16; s <<= 1) acc += __shfl_xor(acc, s, 64);
            if (kc == 0) outb[t * O_ + o] = acc + fcb_v;
        }
    }
}

extern "C" void kernel_launch(void* const* d_in, const int* in_sizes, int n_in,
                              void* d_out, int out_size, void* d_ws, size_t ws_size,
                              hipStream_t stream) {
    const float* x    = (const float*)d_in[0];
    const float* Wih  = (const float*)d_in[1];
    const float* Whh  = (const float*)d_in[2];
    const float* bih  = (const float*)d_in[3];
    const float* bhh  = (const float*)d_in[4];
    const float* fcw  = (const float*)d_in[5];
    const float* fcb  = (const float*)d_in[6];
    float* out = (float*)d_out;

    char* ws = (char*)d_ws;
    uint32_t* qw   = (uint32_t*)(ws + QW_OFF);
    float*    sw1  = (float*)(ws + SW1_OFF);
    float*    sw2  = (float*)(ws + SW2_OFF);
    float*    bias = (float*)(ws + BIAS_OFF);
    uint32_t* xq   = (uint32_t*)(ws + XQ_OFF);
    float*    xs   = (float*)(ws + XS_OFF);

    prep_w<<<G4, 128, 0, stream>>>(Whh, Wih, bih, bhh, qw, sw1, sw2, bias);
    prep_x<<<(B_ * T_) / 64, 256, 0, stream>>>(x, xq, xs);
    lstm_main<<<B_, 512, 0, stream>>>(qw, sw1, sw2, bias, xq, xs, fcw, fcb, out);
}

// Round 2
// 3533.351 us; speedup vs baseline: 1.2715x; 1.2715x over previous
//
#include <hip/hip_runtime.h>
#include <cstdint>

// LSTM fused kernel for MI355X — round 2.
// 64 blocks (1 per batch) x 1024 threads (1 gate-row per thread).
// W_hh/W_ih int8 resident in VGPRs (80 dwords/thread). h broadcast goes via
// GLOBAL memory + scalar s_load into SGPRs (fresh permuted address per step
// -> no K$ staleness), eliminating the LDS-pipe bottleneck of round 1.
// Per-wave h quant scales (4 groups) kill the cross-wave max barrier.
// fc: f16 weights in VGPRs + v_dot2_f32_f16 from a 512-B LDS h buffer.

#define B_  64
#define T_  2048
#define I_  32
#define H_  256
#define G4  1024
#define O_  32

typedef int v16i __attribute__((ext_vector_type(16)));
typedef int v4i  __attribute__((ext_vector_type(4)));
typedef _Float16 h2_t __attribute__((ext_vector_type(2)));

#if __has_builtin(__builtin_amdgcn_sdot4)
__device__ __forceinline__ int dot4(int a, int b, int c) {
    return __builtin_amdgcn_sdot4(a, b, c, false);
}
#else
__device__ __forceinline__ int dot4(int a, int b, int c) {
    c += (int)(int8_t)(a)        * (int)(int8_t)(b);
    c += (int)(int8_t)(a >> 8)   * (int)(int8_t)(b >> 8);
    c += (int)(int8_t)(a >> 16)  * (int)(int8_t)(b >> 16);
    c += (int)(int8_t)(a >> 24)  * (int)(int8_t)(b >> 24);
    return c;
}
#endif

__device__ __forceinline__ float fdot2h(h2_t a, h2_t b, float c) {
#if __has_builtin(__builtin_amdgcn_fdot2)
    return __builtin_amdgcn_fdot2(a, b, c, false);
#else
    return c + (float)a[0] * (float)b[0] + (float)a[1] * (float)b[1];
#endif
}

// ---------------- ws layout (all 256-B aligned) ----------------
// qwhh : uint32 [64][1024]    (0)        262144 B
// qwih : uint32 [16][1024]    (262144)   65536 B  (8 dw A-hi, 8 dw B-lo)
// s1   : float  [1024]        (327680)   4096 B
// s2   : float  [1024]        (331776)   4096 B
// bias : float  [1024]        (335872)   4096 B
// xq   : uint32 [B*T][16]     (339968)   8388608 B
// xs   : float  [B*T]         (8728576)  524288 B
// hbuf : per-block 2049 records x 320 B (9252864)  41963520 B
#define QWHH_OFF 0
#define QWIH_OFF 262144
#define S1_OFF   327680
#define S2_OFF   331776
#define BIAS_OFF 335872
#define XQ_OFF   339968
#define XS_OFF   8728576
#define HBUF_OFF 9252864
#define HREC_STRIDE 320
#define HSLOTS 2049

__device__ __forceinline__ uint32_t pack_q(int q0, int q1, int q2, int q3) {
    return  ((uint32_t)(uint8_t)(int8_t)q0)
          | (((uint32_t)(uint8_t)(int8_t)q1) << 8)
          | (((uint32_t)(uint8_t)(int8_t)q2) << 16)
          | (((uint32_t)(uint8_t)(int8_t)q3) << 24);
}

__device__ __forceinline__ int clamp127(int v) {
    return v < -127 ? -127 : (v > 127 ? 127 : v);
}

// -------- prep: quantize weights (1 block of 64 thr per gate-row) --------
__global__ __launch_bounds__(64) void prep_w(
    const float* __restrict__ Whh, const float* __restrict__ Wih,
    const float* __restrict__ bih, const float* __restrict__ bhh,
    uint32_t* __restrict__ qwhh, uint32_t* __restrict__ qwih,
    float* __restrict__ s1, float* __restrict__ s2, float* __restrict__ bias)
{
    const int r = blockIdx.x;
    const int l = threadIdx.x;

    const float4 wv = ((const float4*)(Whh + r * H_))[l];
    float m = fmaxf(fmaxf(fabsf(wv.x), fabsf(wv.y)), fmaxf(fabsf(wv.z), fabsf(wv.w)));
    #pragma unroll
    for (int s = 1; s < 64; s <<= 1) m = fmaxf(m, __shfl_xor(m, s, 64));
    const float S1 = fmaxf(m, 1e-20f) / 127.f;

    float xm = (l < I_) ? fabsf(Wih[r * I_ + l]) : 0.f;
    #pragma unroll
    for (int s = 1; s < 64; s <<= 1) xm = fmaxf(xm, __shfl_xor(xm, s, 64));
    const float S2 = fmaxf(xm, 1e-20f) / 127.f;

    {
        const float r1 = 1.f / S1;
        qwhh[l * G4 + r] = pack_q(
            clamp127((int)rintf(wv.x * r1)), clamp127((int)rintf(wv.y * r1)),
            clamp127((int)rintf(wv.z * r1)), clamp127((int)rintf(wv.w * r1)));
    }
    if (l < 8) {
        const float4 xw = ((const float4*)(Wih + r * I_))[l];
        const float r2 = 1.f / S2;
        qwih[l * G4 + r] = pack_q(
            clamp127((int)rintf(xw.x * r2)), clamp127((int)rintf(xw.y * r2)),
            clamp127((int)rintf(xw.z * r2)), clamp127((int)rintf(xw.w * r2)));
    } else if (l < 16) {
        const int j = l - 8;
        const float4 xw = ((const float4*)(Wih + r * I_))[j];
        const float r2 = 1.f / S2;
        float v0 = xw.x * r2, v1 = xw.y * r2, v2 = xw.z * r2, v3 = xw.w * r2;
        int a0 = clamp127((int)rintf(v0)), a1 = clamp127((int)rintf(v1));
        int a2 = clamp127((int)rintf(v2)), a3 = clamp127((int)rintf(v3));
        qwih[(8 + j) * G4 + r] = pack_q(
            clamp127((int)rintf((v0 - (float)a0) * 127.f)),
            clamp127((int)rintf((v1 - (float)a1) * 127.f)),
            clamp127((int)rintf((v2 - (float)a2) * 127.f)),
            clamp127((int)rintf((v3 - (float)a3) * 127.f)));
    }
    if (l == 0) { s1[r] = S1; s2[r] = S2; bias[r] = bih[r] + bhh[r]; }
}

// -------- prep: quantize x (64 (b,t) rows per block) --------
__global__ __launch_bounds__(256) void prep_x(
    const float* __restrict__ x, uint32_t* __restrict__ xq, float* __restrict__ xs)
{
    __shared__ float xb[64 * 32];
    const int base = blockIdx.x * 64 * 32;
    for (int i = threadIdx.x; i < 2048; i += 256) xb[i] = x[base + i];
    __syncthreads();
    const int t = threadIdx.x;
    if (t < 64) {
        float m = 0.f;
        for (int k = 0; k < 32; k++) m = fmaxf(m, fabsf(xb[t * 32 + k]));
        const float S = fmaxf(m, 1e-20f) / 127.f;
        const int row = blockIdx.x * 64 + t;
        xs[row] = S;
        const float rS = 1.f / S;
        for (int j = 0; j < 8; j++) {
            int qa[4], qb[4];
            for (int e = 0; e < 4; e++) {
                float v = xb[t * 32 + j * 4 + e] * rS;
                int a = clamp127((int)rintf(v));
                int b = clamp127((int)rintf((v - (float)a) * 127.f));
                qa[e] = a; qb[e] = b;
            }
            xq[row * 16 + j]     = pack_q(qa[0], qa[1], qa[2], qa[3]);
            xq[row * 16 + 8 + j] = pack_q(qb[0], qb[1], qb[2], qb[3]);
        }
    }
}

// x contribution for one (b,t): scalar loads + int8 dots (hi/lo split)
__device__ __forceinline__ float x_contrib(const uint32_t* pxq, const float* pxs,
                                           const uint32_t* wA, const uint32_t* wB,
                                           float S2, float bias_r) {
    v16i xv; int sxi;
    asm volatile("s_load_dwordx16 %0, %2, 0x0\n\t"
                 "s_load_dword %1, %3, 0x0\n\t"
                 "s_waitcnt lgkmcnt(0)"
                 : "=&s"(xv), "=&s"(sxi)
                 : "s"(pxq), "s"(pxs)
                 : "memory");
    int aA = 0, aM = 0;
    #pragma unroll
    for (int j = 0; j < 8; j++) {
        aA = dot4((int)wA[j], xv[j],     aA);
        aM = dot4((int)wA[j], xv[8 + j], aM);
        aM = dot4((int)wB[j], xv[j],     aM);
    }
    return ((float)aA + (float)aM * (1.f / 127.f)) * (S2 * __int_as_float(sxi)) + bias_r;
}

// -------- main: full LSTM + fc, one block per batch, 1024 threads --------
__global__ __launch_bounds__(1024, 4) void lstm_main(
    const uint32_t* __restrict__ qwhh, const uint32_t* __restrict__ qwih,
    const float* __restrict__ s1v, const float* __restrict__ s2v,
    const float* __restrict__ biasv,
    const uint32_t* __restrict__ xq, const float* __restrict__ xs,
    const float* __restrict__ fcw, const float* __restrict__ fcb,
    char* __restrict__ hbuf, float* __restrict__ out)
{
    const int b   = blockIdx.x;
    const int tid = threadIdx.x;

    __shared__ float    gbuf[768];   // f,g,o gate exchange
    __shared__ uint32_t hf16[128];   // h as f16 pairs (for fc)

    // resident int8 weights: row = tid
    uint32_t w[64], wA[8], wB[8];
    #pragma unroll
    for (int d = 0; d < 64; d++) w[d] = qwhh[d * G4 + tid];
    #pragma unroll
    for (int j = 0; j < 8; j++) { wA[j] = qwih[j * G4 + tid]; wB[j] = qwih[(8 + j) * G4 + tid]; }
    const float S1 = s1v[tid], S2 = s2v[tid], bias_r = biasv[tid];

    // fc weights f16 in regs: o_=tid>>5 (0..31), kc=tid&31 -> k in [8kc,8kc+8)
    const int o_ = tid >> 5, kc = tid & 31;
    h2_t fw[4];
    {
        const float* fr = fcw + o_ * H_ + kc * 8;
        #pragma unroll
        for (int j = 0; j < 4; j++) {
            h2_t p; p[0] = (_Float16)fr[2 * j]; p[1] = (_Float16)fr[2 * j + 1];
            fw[j] = p;
        }
    }
    const float fcb_v = fcb[o_];

    char* hb = hbuf + (size_t)b * (HSLOTS * HREC_STRIDE);
    // init slot 2048 = zero h state
    if (tid < H_) hb[2048 * HREC_STRIDE + tid] = 0;
    if (tid >= 256 && tid < 260) ((float*)(hb + 2048 * HREC_STRIDE + 256))[tid - 256] = 0.f;

    const uint32_t* xqb  = xq + (size_t)(b * T_) * 16;
    const float*    xsb  = xs + (size_t)(b * T_);
    float*          outb = out + (size_t)(b * T_) * O_;

    float c_state = 0.f;  // valid for tid < 256
    float x_part  = x_contrib(xqb, xsb, wA, wB, S2, bias_r);

    __syncthreads();  // drain init stores (vmcnt flushed at barrier)

    for (int t = 0; t < T_; t++) {
        // --- scalar broadcast load of h-state (int8 x256 + 4 scales) ---
        const uint32_t slot = (t == 0) ? 2048u : ((uint32_t)(t * 1993) & 2047u);
        const char* hrec = hb + (size_t)slot * HREC_STRIDE;
        v16i h0, h1, h2, h3; v4i scv;
        asm volatile("s_load_dwordx16 %0, %5, 0x0\n\t"
                     "s_load_dwordx16 %1, %5, 0x40\n\t"
                     "s_load_dwordx16 %2, %5, 0x80\n\t"
                     "s_load_dwordx16 %3, %5, 0xc0\n\t"
                     "s_load_dwordx4  %4, %5, 0x100\n\t"
                     "s_waitcnt lgkmcnt(0)"
                     : "=&s"(h0), "=&s"(h1), "=&s"(h2), "=&s"(h3), "=&s"(scv)
                     : "s"(hrec)
                     : "memory");

        int a0 = 0, a1 = 0, a2 = 0, a3 = 0;
        #pragma unroll
        for (int d = 0; d < 16; d++) {
            a0 = dot4((int)w[d],      h0[d], a0);
            a1 = dot4((int)w[16 + d], h1[d], a1);
            a2 = dot4((int)w[32 + d], h2[d], a2);
            a3 = dot4((int)w[48 + d], h3[d], a3);
        }
        const float hsum = (float)a0 * __int_as_float(scv[0])
                         + (float)a1 * __int_as_float(scv[1])
                         + (float)a2 * __int_as_float(scv[2])
                         + (float)a3 * __int_as_float(scv[3]);
        const float gate = hsum * S1 + x_part;

        if (tid >= 256) gbuf[tid - 256] = gate;
        __syncthreads();                                   // A: gates published

        const uint32_t wslot = (uint32_t)((t + 1) * 1993) & 2047u;
        char* hw = hb + (size_t)wslot * HREC_STRIDE;
        float hval = 0.f;
        if (tid < H_) {
            const float gi = gate;
            const float gf = gbuf[tid];
            const float gg = gbuf[256 + tid];
            const float go = gbuf[512 + tid];
            const float i_ = 1.f / (1.f + __expf(-gi));
            const float f_ = 1.f / (1.f + __expf(-gf));
            const float g_ = 2.f / (1.f + __expf(-2.f * gg)) - 1.f;
            const float oo = 1.f / (1.f + __expf(-go));
            c_state = f_ * c_state + i_ * g_;
            const float tc = 2.f / (1.f + __expf(-2.f * c_state)) - 1.f;
            hval = oo * tc;
            ((_Float16*)hf16)[tid] = (_Float16)hval;

            // per-wave (64-elem group) max + int8 quantize + global publish
            float m = fabsf(hval);
            #pragma unroll
            for (int s = 1; s < 64; s <<= 1) m = fmaxf(m, __shfl_xor(m, s, 64));
            m = fmaxf(m, 1e-12f);
            const float rq = 127.f / m;
            const int q = clamp127((int)rintf(hval * rq));
            hw[tid] = (char)(int8_t)q;
            if ((tid & 63) == 0)
                ((float*)(hw + 256))[tid >> 6] = m * (1.f / 127.f);
        }

        // x contribution for t+1 (upper waves run this during nonlinearity)
        if (t < T_ - 1)
            x_part = x_contrib(xqb + (size_t)(t + 1) * 16, xsb + (t + 1),
                               wA, wB, S2, bias_r);

        __syncthreads();                                   // B: h(t+1), hf16 published

        // fc from hf16 (f16 dots, register weights), reduce over 32 lanes
        {
            const uint4 hv = *(const uint4*)(&hf16[4 * kc]);
            union { uint32_t u; h2_t h; } u0, u1, u2, u3;
            u0.u = hv.x; u1.u = hv.y; u2.u = hv.z; u3.u = hv.w;
            float acc = 0.f;
            acc = fdot2h(fw[0], u0.h, acc);
            acc = fdot2h(fw[1], u1.h, acc);
            acc = fdot2h(fw[2], u2.h, acc);
            acc = fdot2h(fw[3], u3.h, acc);
            #pragma unroll
            for (int s = 1; s < 32; s <<= 1) acc += __shfl_xor(acc, s, 64);
            if (kc == 0) outb[t * O_ + o_] = acc + fcb_v;
        }
    }
}

extern "C" void kernel_launch(void* const* d_in, const int* in_sizes, int n_in,
                              void* d_out, int out_size, void* d_ws, size_t ws_size,
                              hipStream_t stream) {
    const float* x    = (const float*)d_in[0];
    const float* Wih  = (const float*)d_in[1];
    const float* Whh  = (const float*)d_in[2];
    const float* bih  = (const float*)d_in[3];
    const float* bhh  = (const float*)d_in[4];
    const float* fcw  = (const float*)d_in[5];
    const float* fcb  = (const float*)d_in[6];
    float* out = (float*)d_out;

    char* ws = (char*)d_ws;
    uint32_t* qwhh = (uint32_t*)(ws + QWHH_OFF);
    uint32_t* qwih = (uint32_t*)(ws + QWIH_OFF);
    float*    s1   = (float*)(ws + S1_OFF);
    float*    s2   = (float*)(ws + S2_OFF);
    float*    bias = (float*)(ws + BIAS_OFF);
    uint32_t* xq   = (uint32_t*)(ws + XQ_OFF);
    float*    xs   = (float*)(ws + XS_OFF);
    char*     hbuf = ws + HBUF_OFF;

    prep_w<<<G4, 64, 0, stream>>>(Whh, Wih, bih, bhh, qwhh, qwih, s1, s2, bias);
    prep_x<<<(B_ * T_) / 64, 256, 0, stream>>>(x, xq, xs);
    lstm_main<<<B_, 1024, 0, stream>>>(qwhh, qwih, s1, s2, bias, xq, xs,
                                       fcw, fcb, hbuf, out);
}